// Round 1
// baseline (540.353 us; speedup 1.0000x reference)
//
#include <hip/hip_runtime.h>

#define GAMMA 0.99f
#define BETA  0.01f
// Problem shape (fixed): B=65536, T=128, A=8.
// One 64-lane wave per batch row; lane l owns timesteps t0=2l, t1=2l+1.

__global__ __launch_bounds__(256, 8) void a3c_loss_kernel(
    const float* __restrict__ values,      // [B,128]
    const float* __restrict__ last_value,  // [B]
    const float* __restrict__ rewards,     // [B,128]
    const float* __restrict__ log_probs,   // [B,128,8]
    const float* __restrict__ entropies,   // [B,128,8]
    const int*   __restrict__ terminal_mask, // [B] (bool -> int32 per harness)
    float* __restrict__ out,               // [B,2] = (actor, critic)
    int B)
{
    const int wave = threadIdx.x >> 6;
    const int lane = threadIdx.x & 63;
    const int b = blockIdx.x * 4 + wave;
    if (b >= B) return;

    // ---- coalesced loads: lane l reads contiguous 8B (v,r) and 64B (lp,ent) ----
    const float2 v2 = reinterpret_cast<const float2*>(values  + (size_t)b * 128)[lane];
    const float2 r2 = reinterpret_cast<const float2*>(rewards + (size_t)b * 128)[lane];
    const float4* lp4 = reinterpret_cast<const float4*>(log_probs + (size_t)b * 1024) + lane * 4;
    const float4* en4 = reinterpret_cast<const float4*>(entropies + (size_t)b * 1024) + lane * 4;
    const float4 la = lp4[0], lb = lp4[1], lc = lp4[2], ld = lp4[3];
    const float4 ea = en4[0], eb = en4[1], ec = en4[2], ed = en4[3];

    const float v0 = v2.x, v1 = v2.y;
    const float r0 = r2.x, r1 = r2.y;
    // sum over A=8: lp0 covers t0 (elements 16l..16l+7), lp1 covers t1
    const float lp0 = (la.x + la.y + la.z + la.w) + (lb.x + lb.y + lb.z + lb.w);
    const float lp1 = (lc.x + lc.y + lc.z + lc.w) + (ld.x + ld.y + ld.z + ld.w);
    const float esum = (ea.x + ea.y + ea.z + ea.w) + (eb.x + eb.y + eb.z + eb.w)
                     + (ec.x + ec.y + ec.z + ec.w) + (ed.x + ed.y + ed.z + ed.w);

    // Bootstrap value (wave-uniform)
    const float R0 = (terminal_mask[b] != 0) ? 0.0f : last_value[b];

    // v_next at t1 = v[2l+2] = lane (l+1)'s v0; lane 63 -> R0
    float vnext1 = __shfl_down(v0, 1, 64);
    if (lane == 63) vnext1 = R0;
    const float delta1 = r1 + GAMMA * vnext1 - v1;
    const float delta0 = r0 + GAMMA * v1    - v0;   // v_next at t0 is v1 (local)

    // ---- per-lane affine segment maps (applied in descending t: t1 then t0) ----
    // R:   x -> gamma^2 * x + (gamma*r1 + r0)
    // gae: x -> gamma^2 * x + (gamma*delta1 + delta0)
    float m  = GAMMA * GAMMA;
    float cR = fmaf(GAMMA, r1, r0);
    float cG = fmaf(GAMMA, delta1, delta0);

    // Inclusive suffix scan of map composition: S_l = M_l o S_{l+1}
    // (f o g) = (m_f*m_g, m_f*c_g + c_f)
    #pragma unroll
    for (int d = 1; d < 64; d <<= 1) {
        const float om  = __shfl_down(m,  d, 64);
        const float ocR = __shfl_down(cR, d, 64);
        const float ocG = __shfl_down(cG, d, 64);
        if (lane + d < 64) {
            cR = fmaf(m, ocR, cR);
            cG = fmaf(m, ocG, cG);
            m  = m * om;
        }
    }
    // Exclusive suffix (incoming carry) = S_{l+1}; lane 63 gets identity
    float pm  = __shfl_down(m,  1, 64);
    float pcR = __shfl_down(cR, 1, 64);
    float pcG = __shfl_down(cG, 1, 64);
    if (lane == 63) { pm = 1.0f; pcR = 0.0f; pcG = 0.0f; }

    const float Rin = fmaf(pm, R0, pcR);   // R entering this lane's segment
    const float gin = pcG;                 // gae entering (gae starts at 0)

    // Evaluate the two local timesteps (t1 first, then t0)
    const float R1   = fmaf(GAMMA, Rin, r1);
    const float Rt0  = fmaf(GAMMA, R1,  r0);
    const float adv1 = R1  - v1;
    const float adv0 = Rt0 - v0;
    float critic = 0.5f * (adv1 * adv1 + adv0 * adv0);

    const float g1 = fmaf(GAMMA, gin, delta1);
    const float g0 = fmaf(GAMMA, g1,  delta0);
    float actor = -(lp1 * g1 + lp0 * g0) - BETA * esum;

    // ---- wave reduction over the 64 lanes ----
    #pragma unroll
    for (int d = 32; d >= 1; d >>= 1) {
        actor  += __shfl_down(actor,  d, 64);
        critic += __shfl_down(critic, d, 64);
    }

    if (lane == 0) {
        reinterpret_cast<float2*>(out)[b] = make_float2(actor, critic);
    }
}

extern "C" void kernel_launch(void* const* d_in, const int* in_sizes, int n_in,
                              void* d_out, int out_size, void* d_ws, size_t ws_size,
                              hipStream_t stream) {
    const float* values      = (const float*)d_in[0];
    const float* last_value  = (const float*)d_in[1];
    const float* rewards     = (const float*)d_in[2];
    const float* log_probs   = (const float*)d_in[3];
    const float* entropies   = (const float*)d_in[4];
    const int*   terminal    = (const int*)d_in[5];
    float* out = (float*)d_out;

    const int B = in_sizes[1];              // 65536
    const int blocks = (B + 3) / 4;         // 4 waves (batches) per 256-thread block

    a3c_loss_kernel<<<blocks, 256, 0, stream>>>(
        values, last_value, rewards, log_probs, entropies, terminal, out, B);
}

// Round 2
// 533.909 us; speedup vs baseline: 1.0121x; 1.0121x over previous
//
#include <hip/hip_runtime.h>

#define GAMMA 0.99f
#define BETA  0.01f
// Problem shape (fixed): B=65536, T=128, A=8.
// One 64-lane wave per batch row; lane l owns timesteps t0=2l, t1=2l+1 for the
// scan. lp/ent are loaded fully coalesced (lane l -> float4 index l+64k) and
// the gae weights are redistributed with bpermute after the scan.

__global__ __launch_bounds__(256, 6) void a3c_loss_kernel(
    const float* __restrict__ values,        // [B,128]
    const float* __restrict__ last_value,    // [B]
    const float* __restrict__ rewards,       // [B,128]
    const float* __restrict__ log_probs,     // [B,128,8]
    const float* __restrict__ entropies,     // [B,128,8]
    const int*   __restrict__ terminal_mask, // [B]
    float* __restrict__ out,                 // [B,2] = (actor, critic)
    int B)
{
    const int wave = threadIdx.x >> 6;
    const int lane = threadIdx.x & 63;
    const int b = blockIdx.x * 4 + wave;
    if (b >= B) return;

    // ---- issue scan-critical loads first ----
    const float2 v2 = reinterpret_cast<const float2*>(values  + (size_t)b * 128)[lane];
    const float2 r2 = reinterpret_cast<const float2*>(rewards + (size_t)b * 128)[lane];
    const float lv  = last_value[b];
    const int   tm  = terminal_mask[b];

    // ---- fully coalesced lp/ent loads: lane l reads float4 at l+64k ----
    const float4* lp4 = reinterpret_cast<const float4*>(log_probs + (size_t)b * 1024);
    const float4* en4 = reinterpret_cast<const float4*>(entropies + (size_t)b * 1024);
    const float4 L0 = lp4[lane      ];
    const float4 L1 = lp4[lane +  64];
    const float4 L2 = lp4[lane + 128];
    const float4 L3 = lp4[lane + 192];
    const float4 E0 = en4[lane      ];
    const float4 E1 = en4[lane +  64];
    const float4 E2 = en4[lane + 128];
    const float4 E3 = en4[lane + 192];

    const float v0 = v2.x, v1 = v2.y;
    const float r0 = r2.x, r1 = r2.y;

    // Bootstrap value (wave-uniform)
    const float R0 = (tm != 0) ? 0.0f : lv;

    // v_next at t1 = v[2l+2] = lane (l+1)'s v0; lane 63 -> R0
    float vnext1 = __shfl_down(v0, 1, 64);
    if (lane == 63) vnext1 = R0;
    const float delta1 = r1 + GAMMA * vnext1 - v1;
    const float delta0 = r0 + GAMMA * v1    - v0;   // v_next at t0 is v1 (local)

    // ---- per-lane affine segment maps (applied in descending t: t1 then t0) ----
    // R:   x -> gamma^2 * x + (gamma*r1 + r0)
    // gae: x -> gamma^2 * x + (gamma*delta1 + delta0)
    float m  = GAMMA * GAMMA;
    float cR = fmaf(GAMMA, r1, r0);
    float cG = fmaf(GAMMA, delta1, delta0);

    // Inclusive suffix scan of map composition: S_l = M_l o S_{l+1}
    #pragma unroll
    for (int d = 1; d < 64; d <<= 1) {
        const float om  = __shfl_down(m,  d, 64);
        const float ocR = __shfl_down(cR, d, 64);
        const float ocG = __shfl_down(cG, d, 64);
        if (lane + d < 64) {
            cR = fmaf(m, ocR, cR);
            cG = fmaf(m, ocG, cG);
            m  = m * om;
        }
    }
    // Exclusive suffix (incoming carry) = S_{l+1}; lane 63 gets identity
    float pm  = __shfl_down(m,  1, 64);
    float pcR = __shfl_down(cR, 1, 64);
    float pcG = __shfl_down(cG, 1, 64);
    if (lane == 63) { pm = 1.0f; pcR = 0.0f; pcG = 0.0f; }

    const float Rin = fmaf(pm, R0, pcR);   // R entering this lane's segment
    const float gin = pcG;                 // gae entering (gae starts at 0)

    // Evaluate the two local timesteps (t1 first, then t0)
    const float R1   = fmaf(GAMMA, Rin, r1);
    const float Rt0  = fmaf(GAMMA, R1,  r0);
    const float adv1 = R1  - v1;
    const float adv0 = Rt0 - v0;
    float critic = 0.5f * (adv1 * adv1 + adv0 * adv0);

    const float g1 = fmaf(GAMMA, gin, delta1);  // gae at t=2l+1
    const float g0 = fmaf(GAMMA, g1,  delta0);  // gae at t=2l

    // ---- redistribute gae to the coalesced-lp layout ----
    // float4 index j = lane + 64k covers t = j>>1, holder lane h = j>>2 =
    // (lane>>2)+16k, parity (t&1) = (lane>>1)&1 selects g0 (even t) vs g1.
    const int par = (lane >> 1) & 1;
    const int hb  = lane >> 2;
    float actor = 0.0f;
    {
        const int h0 = hb;
        const int h1 = hb + 16;
        const int h2 = hb + 32;
        const int h3 = hb + 48;
        const float gA0 = __shfl(g0, h0, 64), gB0 = __shfl(g1, h0, 64);
        const float gA1 = __shfl(g0, h1, 64), gB1 = __shfl(g1, h1, 64);
        const float gA2 = __shfl(g0, h2, 64), gB2 = __shfl(g1, h2, 64);
        const float gA3 = __shfl(g0, h3, 64), gB3 = __shfl(g1, h3, 64);
        const float gk0 = par ? gB0 : gA0;
        const float gk1 = par ? gB1 : gA1;
        const float gk2 = par ? gB2 : gA2;
        const float gk3 = par ? gB3 : gA3;
        const float sL0 = (L0.x + L0.y) + (L0.z + L0.w);
        const float sL1 = (L1.x + L1.y) + (L1.z + L1.w);
        const float sL2 = (L2.x + L2.y) + (L2.z + L2.w);
        const float sL3 = (L3.x + L3.y) + (L3.z + L3.w);
        actor = -(sL0 * gk0 + sL1 * gk1 + sL2 * gk2 + sL3 * gk3);
    }
    // Entropy: pure full-row sum, no redistribution needed.
    const float esum = ((E0.x + E0.y) + (E0.z + E0.w)) + ((E1.x + E1.y) + (E1.z + E1.w))
                     + ((E2.x + E2.y) + (E2.z + E2.w)) + ((E3.x + E3.y) + (E3.z + E3.w));
    actor = fmaf(-BETA, esum, actor);

    // ---- wave reduction over the 64 lanes ----
    #pragma unroll
    for (int d = 32; d >= 1; d >>= 1) {
        actor  += __shfl_down(actor,  d, 64);
        critic += __shfl_down(critic, d, 64);
    }

    if (lane == 0) {
        reinterpret_cast<float2*>(out)[b] = make_float2(actor, critic);
    }
}

extern "C" void kernel_launch(void* const* d_in, const int* in_sizes, int n_in,
                              void* d_out, int out_size, void* d_ws, size_t ws_size,
                              hipStream_t stream) {
    const float* values      = (const float*)d_in[0];
    const float* last_value  = (const float*)d_in[1];
    const float* rewards     = (const float*)d_in[2];
    const float* log_probs   = (const float*)d_in[3];
    const float* entropies   = (const float*)d_in[4];
    const int*   terminal    = (const int*)d_in[5];
    float* out = (float*)d_out;

    const int B = in_sizes[1];              // 65536
    const int blocks = (B + 3) / 4;         // 4 waves (batches) per 256-thread block

    a3c_loss_kernel<<<blocks, 256, 0, stream>>>(
        values, last_value, rewards, log_probs, entropies, terminal, out, B);
}